// Round 3
// baseline (982.050 us; speedup 1.0000x reference)
//
#include <hip/hip_runtime.h>
#include <hip/hip_bf16.h>
#include <math.h>

// MoE: B=4 S=2048 D=1024 E=8 K=2 H=4096
// R6: revert to proven 128x128xBK64 grouped GEMMs (R3 geometry, 26% MfmaUtil at
//     2.6 blocks/CU) with two identified fixes:
//     (1) gemm2 atomic-ectomy: R4/R5 showed a ~105 G atomics/s chip ceiling;
//         gemm2 now stores y[slot] with plain f32 stores; combine kernel sums
//         the 2 slots per token (map built in scatter). y aliases W1t (dead
//         after gemm1, exactly 67MB).
//     (2) T3-minimum double-buffered K-loop: stage tile t+1 FIRST, ds_read +
//         MFMA tile t, ONE __syncthreads per tile (vmcnt drain covered by the
//         ~600cy of MFMA above it + 2 blocks/CU TLP). 64KiB LDS.
//     Also: transposes fused into one launch, scan folded into router's last
//     block, out-memset dropped (combine writes all of out). 10 -> 8 launches.

#define TOK     8192
#define DMODEL  1024
#define NEXP    8
#define HFF     4096
#define NASSIGN 16384
#define SLOTPAD 16512   // NASSIGN + 128 pad rows (partial-tile overreads)
#define BM      128
#define BN      128
#define BK      64
#define MAXRT   135     // sum_e ceil(n_e/128) <= 16384/128 + 7

typedef __attribute__((ext_vector_type(8))) short s16x8;
typedef __attribute__((ext_vector_type(4))) float f32x4;

__device__ __forceinline__ void gll16(const void* g, void* l) {
  __builtin_amdgcn_global_load_lds((const __attribute__((address_space(1))) void*)g,
                                   (__attribute__((address_space(3))) void*)l, 16, 0, 0);
}

// ---------- fused transpose + f32->bf16: W1 [D][H] -> W1t [H][D], W2 [H][D] -> W2t [D][H] ----------
__global__ void transpose_cvt(const float* __restrict__ W1, const float* __restrict__ W2,
                              __hip_bfloat16* __restrict__ W1t, __hip_bfloat16* __restrict__ W2t) {
  __shared__ float t[64][65];
  const int z = blockIdx.y;
  const float* src; __hip_bfloat16* dst; int R, C, bx, by;
  if (z < 8) {
    R = DMODEL; C = HFF;
    src = W1 + (size_t)z * R * C; dst = W1t + (size_t)z * R * C;
    bx = blockIdx.x & 63; by = blockIdx.x >> 6;     // 64 x 16 tiles
  } else {
    R = HFF; C = DMODEL;
    src = W2 + (size_t)(z - 8) * R * C; dst = W2t + (size_t)(z - 8) * R * C;
    bx = blockIdx.x & 15; by = blockIdx.x >> 4;     // 16 x 64 tiles
  }
  const int r0 = by * 64, c0 = bx * 64;
  const int tc = threadIdx.x & 63, tr = threadIdx.x >> 6;  // tr in 0..3
#pragma unroll
  for (int i = 0; i < 16; ++i) {
    int r = i * 4 + tr;
    t[r][tc] = src[(size_t)(r0 + r) * C + c0 + tc];
  }
  __syncthreads();
  const int jl = (threadIdx.x & 15) * 4;   // row offset within tile
  const int cw = threadIdx.x >> 4;         // 0..15: col within pass
#pragma unroll
  for (int p = 0; p < 4; ++p) {
    const int cc = p * 16 + cw;
    union { ushort4 u; __hip_bfloat16 h[4]; } o;
#pragma unroll
    for (int u = 0; u < 4; ++u) o.h[u] = __float2bfloat16(t[jl + u][cc]);
    *(ushort4*)(dst + (size_t)(c0 + cc) * R + r0 + jl) = o.u;
  }
}

// ---------- router: fp32 logits -> softmax -> top-2; last-done block performs the scan ----------
__global__ void router_kernel(const float* __restrict__ x, const float* __restrict__ Wg,
                              const float* __restrict__ bg, int* __restrict__ idx,
                              float* __restrict__ wtok, int* ctrl) {
  __shared__ int scnt[NEXP];
  if (threadIdx.x < NEXP) scnt[threadIdx.x] = 0;
  __syncthreads();
  const int wave = threadIdx.x >> 6, lane = threadIdx.x & 63;
  const int t = blockIdx.x * 4 + wave;
  float acc[NEXP];
#pragma unroll
  for (int e = 0; e < NEXP; ++e) acc[e] = 0.f;
  const float* xr = x + (size_t)t * DMODEL + lane * 16;
#pragma unroll
  for (int j = 0; j < 4; ++j) {
    float4 xv = *(const float4*)(xr + j * 4);
    const float* wr = Wg + (size_t)(lane * 16 + j * 4) * NEXP;
#pragma unroll
    for (int u = 0; u < 4; ++u) {
      float xs = (&xv.x)[u];
      float4 w0 = *(const float4*)(wr + u * NEXP);
      float4 w1 = *(const float4*)(wr + u * NEXP + 4);
      acc[0] += xs * w0.x; acc[1] += xs * w0.y; acc[2] += xs * w0.z; acc[3] += xs * w0.w;
      acc[4] += xs * w1.x; acc[5] += xs * w1.y; acc[6] += xs * w1.z; acc[7] += xs * w1.w;
    }
  }
#pragma unroll
  for (int off = 32; off >= 1; off >>= 1) {
#pragma unroll
    for (int e = 0; e < NEXP; ++e) acc[e] += __shfl_xor(acc[e], off, 64);
  }
  if (lane == 0) {
    float l[NEXP], m = -1e30f;
#pragma unroll
    for (int e = 0; e < NEXP; ++e) { l[e] = acc[e] + bg[e]; m = fmaxf(m, l[e]); }
    float p[NEXP], s = 0.f;
#pragma unroll
    for (int e = 0; e < NEXP; ++e) { p[e] = expf(l[e] - m); s += p[e]; }
    float inv = 1.f / s;
#pragma unroll
    for (int e = 0; e < NEXP; ++e) p[e] *= inv;
    int i0 = 0; float v0 = p[0];
#pragma unroll
    for (int e = 1; e < NEXP; ++e) if (p[e] > v0) { v0 = p[e]; i0 = e; }
    int i1 = -1; float v1 = -1e30f;
#pragma unroll
    for (int e = 0; e < NEXP; ++e) if (e != i0 && p[e] > v1) { v1 = p[e]; i1 = e; }
    idx[2 * t] = i0; idx[2 * t + 1] = i1;
    wtok[2 * t] = v0; wtok[2 * t + 1] = v1;
    atomicAdd(&scnt[i0], 1); atomicAdd(&scnt[i1], 1);
  }
  __syncthreads();
  if (threadIdx.x < NEXP) atomicAdd(&ctrl[threadIdx.x], scnt[threadIdx.x]);
  // ---- folded scan: last block to finish builds expOff/tileRowOff/cursor ----
  if (threadIdx.x == 0) {
    __threadfence();
    const int done = atomicAdd(&ctrl[63], 1);
    if (done == (int)gridDim.x - 1) {
      int c[NEXP];
#pragma unroll
      for (int e = 0; e < NEXP; ++e) c[e] = atomicAdd(&ctrl[e], 0);  // coherent read
      int eo = 0, tr = 0;
      ctrl[16] = 0; ctrl[26] = 0;
#pragma unroll
      for (int e = 0; e < NEXP; ++e) {
        ctrl[8 + e] = eo;            // cursor
        eo += c[e]; tr += (c[e] + BM - 1) / BM;
        ctrl[17 + e] = eo;           // expOff[e+1]
        ctrl[27 + e] = tr;           // tileRowOff[e+1]
      }
    }
  }
}

__global__ void scatter_kernel(const int* __restrict__ idx, const float* __restrict__ wtok,
                               int* ctrl, int* __restrict__ perm, int* __restrict__ ts,
                               float* __restrict__ wslot) {
  __shared__ int lcnt[NEXP];
  __shared__ int lbase[NEXP];
  const int t = blockIdx.x * 256 + threadIdx.x;
  if (threadIdx.x < NEXP) lcnt[threadIdx.x] = 0;
  __syncthreads();
  const int e0 = idx[2 * t], e1 = idx[2 * t + 1];
  const int l0 = atomicAdd(&lcnt[e0], 1);
  const int l1 = atomicAdd(&lcnt[e1], 1);
  __syncthreads();
  if (threadIdx.x < NEXP)
    lbase[threadIdx.x] = atomicAdd(&ctrl[8 + threadIdx.x], lcnt[threadIdx.x]);
  __syncthreads();
  const int s0 = lbase[e0] + l0, s1 = lbase[e1] + l1;
  perm[s0] = t; perm[s1] = t;
  ts[2 * t] = s0; ts[2 * t + 1] = s1;
  wslot[s0] = wtok[2 * t]; wslot[s1] = wtok[2 * t + 1];
}

__global__ void gather_cvt_x(const float* __restrict__ x, const int* __restrict__ perm,
                             __hip_bfloat16* __restrict__ xg) {
  const int slot = blockIdx.x;
  const int t = perm[slot];
  const float4 v = *(const float4*)(x + (size_t)t * DMODEL + threadIdx.x * 4);
  union { ushort4 u; __hip_bfloat16 h[4]; } o;
  o.h[0] = __float2bfloat16(v.x); o.h[1] = __float2bfloat16(v.y);
  o.h[2] = __float2bfloat16(v.z); o.h[3] = __float2bfloat16(v.w);
  *(ushort4*)(xg + (size_t)slot * DMODEL + threadIdx.x * 4) = o.u;
}

// ---- LDS layout (per buffer, 128 rows x BK=64): row r, 8 chunks of 8 bf16 (16B);
// chunk kc stored at slot kc ^ (r&7). Stage chunk s = tid+256*i: r=s>>3, sl=s&7,
// kc=sl^(r&7) -> lane-contiguous LDS dests (gll16-legal), pre-swizzled global src.
// Fragment read (k-half h, quad q): elem off = r*64 + (q^(r&7))*8, ^(h*32).
//
// K-loop (T3-minimum, double-buffered):
//   prologue: STAGE(buf0, t=0); __syncthreads;
//   for t: { if(t+1<NT) STAGE(buf[(t+1)&1], t+1);   // issued FIRST
//            ds_read 16 b128 from buf[t&1]; setprio(1); 32 MFMA; setprio(0);
//            if(t+1<NT) __syncthreads(); }          // one drain per tile

// ---------- grouped GEMM1: h = gelu(xg @ W1t^T + b1) ----------
__global__ __launch_bounds__(256, 2) void gemm1_kernel(
    const __hip_bfloat16* __restrict__ xg, const __hip_bfloat16* __restrict__ w1t,
    const float* __restrict__ b1, __hip_bfloat16* __restrict__ hbuf,
    const int* __restrict__ ctrl) {
  const int* expOff = ctrl + 16;
  const int* tro = ctrl + 26;
  const int w = blockIdx.x;
  const int rt = w >> 5, nt = w & 31;   // rt-major
  if (rt >= tro[NEXP]) return;
  int e = 0;
#pragma unroll
  for (int q = 1; q < NEXP; ++q) if (tro[q] <= rt) e = q;
  const int rowBase = expOff[e] + (rt - tro[e]) * BM;
  const int rowEnd = expOff[e + 1];

  __shared__ __hip_bfloat16 lA[2 * BM * BK];
  __shared__ __hip_bfloat16 lB[2 * BN * BK];

  const int tid = threadIdx.x;
  const int lane = tid & 63, wave = tid >> 6;
  const int quad = lane >> 4, lm = lane & 15;
  const int waveM = (wave >> 1) * 64, waveN = (wave & 1) * 64;

  f32x4 acc[4][4];
#pragma unroll
  for (int a = 0; a < 4; ++a)
#pragma unroll
    for (int b = 0; b < 4; ++b) acc[a][b] = (f32x4){0.f, 0.f, 0.f, 0.f};

  const __hip_bfloat16* bbase = w1t + (size_t)e * HFF * DMODEL + (size_t)nt * BN * DMODEL;
  const __hip_bfloat16* gA[4]; const __hip_bfloat16* gB[4];
#pragma unroll
  for (int i = 0; i < 4; ++i) {
    const int s = tid + 256 * i;
    const int r = s >> 3, sl = s & 7, kc = sl ^ (r & 7);
    gA[i] = xg + (size_t)(rowBase + r) * DMODEL + kc * 8;
    gB[i] = bbase + (size_t)r * DMODEL + kc * 8;
  }

  int aOff[4], bOff[4];   // h=0 element offsets; h=1 = ^32
#pragma unroll
  for (int tm = 0; tm < 4; ++tm) {
    int r = waveM + tm * 16 + lm;
    aOff[tm] = r * 64 + (quad ^ (r & 7)) * 8;
  }
#pragma unroll
  for (int tn = 0; tn < 4; ++tn) {
    int r = waveN + tn * 16 + lm;
    bOff[tn] = r * 64 + (quad ^ (r & 7)) * 8;
  }

  // prologue: stage tile 0 into buffer 0
#pragma unroll
  for (int i = 0; i < 4; ++i) {
    gll16(gA[i], lA + tid * 8 + i * 2048);
    gll16(gB[i], lB + tid * 8 + i * 2048);
    gA[i] += BK; gB[i] += BK;
  }
  __syncthreads();

  const int NTI = DMODEL / BK;  // 16
  for (int kt = 0; kt < NTI; ++kt) {
    // stage next tile FIRST (into the other buffer)
    if (kt + 1 < NTI) {
      const int nb = (kt + 1) & 1;
#pragma unroll
      for (int i = 0; i < 4; ++i) {
        gll16(gA[i], lA + nb * 8192 + tid * 8 + i * 2048);
        gll16(gB[i], lB + nb * 8192 + tid * 8 + i * 2048);
        gA[i] += BK; gB[i] += BK;
      }
    }
    const __hip_bfloat16* ba = lA + (kt & 1) * 8192;
    const __hip_bfloat16* bb = lB + (kt & 1) * 8192;
    s16x8 af[2][4], bfr[2][4];
#pragma unroll
    for (int h = 0; h < 2; ++h) {
#pragma unroll
      for (int tm = 0; tm < 4; ++tm) af[h][tm] = *(const s16x8*)(ba + (aOff[tm] ^ (h * 32)));
#pragma unroll
      for (int tn = 0; tn < 4; ++tn) bfr[h][tn] = *(const s16x8*)(bb + (bOff[tn] ^ (h * 32)));
    }
    __builtin_amdgcn_s_setprio(1);
#pragma unroll
    for (int h = 0; h < 2; ++h)
#pragma unroll
      for (int tm = 0; tm < 4; ++tm)
#pragma unroll
        for (int tn = 0; tn < 4; ++tn)
          acc[tm][tn] = __builtin_amdgcn_mfma_f32_16x16x32_bf16(af[h][tm], bfr[h][tn],
                                                                acc[tm][tn], 0, 0, 0);
    __builtin_amdgcn_s_setprio(0);
    if (kt + 1 < NTI) __syncthreads();   // drains vmcnt: next tile ready
  }

  const int colBase = nt * BN + waveN;
  float bv[4];
#pragma unroll
  for (int tn = 0; tn < 4; ++tn) bv[tn] = b1[e * HFF + colBase + tn * 16 + lm];
#pragma unroll
  for (int tm = 0; tm < 4; ++tm) {
    const int rb = rowBase + waveM + tm * 16 + quad * 4;
#pragma unroll
    for (int reg = 0; reg < 4; ++reg) {
      const int row = rb + reg;
      if (row < rowEnd) {
#pragma unroll
        for (int tn = 0; tn < 4; ++tn) {
          float v = acc[tm][tn][reg] + bv[tn];
          v = 0.5f * v * (1.f + erff(v * 0.70710678118654752f));  // exact gelu
          hbuf[(size_t)row * HFF + colBase + tn * 16 + lm] = __float2bfloat16(v);
        }
      }
    }
  }
}

// ---------- grouped GEMM2: y[slot] = (h @ W2t^T + b2) * w_gate   (plain f32 stores) ----------
__global__ __launch_bounds__(256, 2) void gemm2_kernel(
    const __hip_bfloat16* __restrict__ hbuf, const __hip_bfloat16* __restrict__ w2t,
    const float* __restrict__ b2, const float* __restrict__ wslot,
    float* __restrict__ y, const int* __restrict__ ctrl) {
  const int* expOff = ctrl + 16;
  const int* tro = ctrl + 26;
  const int w = blockIdx.x;
  const int rt = w >> 3, nt = w & 7;
  if (rt >= tro[NEXP]) return;
  int e = 0;
#pragma unroll
  for (int q = 1; q < NEXP; ++q) if (tro[q] <= rt) e = q;
  const int rowBase = expOff[e] + (rt - tro[e]) * BM;
  const int rowEnd = expOff[e + 1];

  __shared__ __hip_bfloat16 lA[2 * BM * BK];
  __shared__ __hip_bfloat16 lB[2 * BN * BK];

  const int tid = threadIdx.x;
  const int lane = tid & 63, wave = tid >> 6;
  const int quad = lane >> 4, lm = lane & 15;
  const int waveM = (wave >> 1) * 64, waveN = (wave & 1) * 64;

  f32x4 acc[4][4];
#pragma unroll
  for (int a = 0; a < 4; ++a)
#pragma unroll
    for (int b = 0; b < 4; ++b) acc[a][b] = (f32x4){0.f, 0.f, 0.f, 0.f};

  const __hip_bfloat16* bbase = w2t + (size_t)e * DMODEL * HFF + (size_t)nt * BN * HFF;
  const __hip_bfloat16* gA[4]; const __hip_bfloat16* gB[4];
#pragma unroll
  for (int i = 0; i < 4; ++i) {
    const int s = tid + 256 * i;
    const int r = s >> 3, sl = s & 7, kc = sl ^ (r & 7);
    gA[i] = hbuf + (size_t)(rowBase + r) * HFF + kc * 8;
    gB[i] = bbase + (size_t)r * HFF + kc * 8;
  }

  int aOff[4], bOff[4];
#pragma unroll
  for (int tm = 0; tm < 4; ++tm) {
    int r = waveM + tm * 16 + lm;
    aOff[tm] = r * 64 + (quad ^ (r & 7)) * 8;
  }
#pragma unroll
  for (int tn = 0; tn < 4; ++tn) {
    int r = waveN + tn * 16 + lm;
    bOff[tn] = r * 64 + (quad ^ (r & 7)) * 8;
  }

#pragma unroll
  for (int i = 0; i < 4; ++i) {
    gll16(gA[i], lA + tid * 8 + i * 2048);
    gll16(gB[i], lB + tid * 8 + i * 2048);
    gA[i] += BK; gB[i] += BK;
  }
  __syncthreads();

  const int NTI = HFF / BK;  // 64
  for (int kt = 0; kt < NTI; ++kt) {
    if (kt + 1 < NTI) {
      const int nb = (kt + 1) & 1;
#pragma unroll
      for (int i = 0; i < 4; ++i) {
        gll16(gA[i], lA + nb * 8192 + tid * 8 + i * 2048);
        gll16(gB[i], lB + nb * 8192 + tid * 8 + i * 2048);
        gA[i] += BK; gB[i] += BK;
      }
    }
    const __hip_bfloat16* ba = lA + (kt & 1) * 8192;
    const __hip_bfloat16* bb = lB + (kt & 1) * 8192;
    s16x8 af[2][4], bfr[2][4];
#pragma unroll
    for (int h = 0; h < 2; ++h) {
#pragma unroll
      for (int tm = 0; tm < 4; ++tm) af[h][tm] = *(const s16x8*)(ba + (aOff[tm] ^ (h * 32)));
#pragma unroll
      for (int tn = 0; tn < 4; ++tn) bfr[h][tn] = *(const s16x8*)(bb + (bOff[tn] ^ (h * 32)));
    }
    __builtin_amdgcn_s_setprio(1);
#pragma unroll
    for (int h = 0; h < 2; ++h)
#pragma unroll
      for (int tm = 0; tm < 4; ++tm)
#pragma unroll
        for (int tn = 0; tn < 4; ++tn)
          acc[tm][tn] = __builtin_amdgcn_mfma_f32_16x16x32_bf16(af[h][tm], bfr[h][tn],
                                                                acc[tm][tn], 0, 0, 0);
    __builtin_amdgcn_s_setprio(0);
    if (kt + 1 < NTI) __syncthreads();
  }

  const int colBase = nt * BN + waveN;
  float bv[4];
#pragma unroll
  for (int tn = 0; tn < 4; ++tn) bv[tn] = b2[e * DMODEL + colBase + tn * 16 + lm];
#pragma unroll
  for (int tm = 0; tm < 4; ++tm) {
    const int rb = rowBase + waveM + tm * 16 + quad * 4;
#pragma unroll
    for (int reg = 0; reg < 4; ++reg) {
      const int row = rb + reg;
      if (row < rowEnd) {
        const float wr = wslot[row];
        float* yr = y + (size_t)row * DMODEL + colBase;
#pragma unroll
        for (int tn = 0; tn < 4; ++tn)
          yr[tn * 16 + lm] = (acc[tm][tn][reg] + bv[tn]) * wr;
      }
    }
  }
}

// ---------- combine: out[t] = y[slot0(t)] + y[slot1(t)]  (w already applied) ----------
__global__ void combine_kernel(const float* __restrict__ y, const int* __restrict__ ts,
                               float* __restrict__ out) {
  const int t = blockIdx.x;
  const int s0 = ts[2 * t], s1 = ts[2 * t + 1];
  const int c = threadIdx.x * 4;
  const float4 a = *(const float4*)(y + (size_t)s0 * DMODEL + c);
  const float4 b = *(const float4*)(y + (size_t)s1 * DMODEL + c);
  float4 r; r.x = a.x + b.x; r.y = a.y + b.y; r.z = a.z + b.z; r.w = a.w + b.w;
  *(float4*)(out + (size_t)t * DMODEL + c) = r;
}

extern "C" void kernel_launch(void* const* d_in, const int* in_sizes, int n_in,
                              void* d_out, int out_size, void* d_ws, size_t ws_size,
                              hipStream_t stream) {
  const float* x  = (const float*)d_in[0];
  const float* Wg = (const float*)d_in[1];
  const float* bg = (const float*)d_in[2];
  const float* W1 = (const float*)d_in[3];
  const float* b1 = (const float*)d_in[4];
  const float* W2 = (const float*)d_in[5];
  const float* b2 = (const float*)d_in[6];
  float* out = (float*)d_out;

  char* ws = (char*)d_ws;
  size_t off = 0;
  auto take = [&](size_t bytes) -> char* {
    char* p = ws + off;
    off = (off + bytes + 255) & ~(size_t)255;
    return p;
  };
  int*   ctrl  = (int*)take(64 * sizeof(int));
  int*   idx   = (int*)take((size_t)TOK * 2 * 4);
  float* wtok  = (float*)take((size_t)TOK * 2 * 4);
  int*   perm  = (int*)take((size_t)SLOTPAD * 4);
  int*   ts    = (int*)take((size_t)TOK * 2 * 4);
  float* wslot = (float*)take((size_t)SLOTPAD * 4);
  __hip_bfloat16* W1t = (__hip_bfloat16*)take((size_t)NEXP * HFF * DMODEL * 2);
  __hip_bfloat16* W2t = (__hip_bfloat16*)take((size_t)NEXP * DMODEL * HFF * 2);
  __hip_bfloat16* xgb = (__hip_bfloat16*)take((size_t)SLOTPAD * DMODEL * 2);
  __hip_bfloat16* hb  = (__hip_bfloat16*)take((size_t)SLOTPAD * HFF * 2);
  float* y = (float*)W1t;   // W1t is dead after gemm1; y = 16384*1024*4B = 67MB = |W1t|
  (void)ws_size; (void)in_sizes; (void)n_in; (void)out_size;

  hipMemsetAsync(ctrl, 0, 64 * sizeof(int), stream);
  transpose_cvt<<<dim3(1024, 16), 256, 0, stream>>>(W1, W2, W1t, W2t);
  router_kernel<<<TOK / 4, 256, 0, stream>>>(x, Wg, bg, idx, wtok, ctrl);
  scatter_kernel<<<TOK / 256, 256, 0, stream>>>(idx, wtok, ctrl, perm, ts, wslot);
  gather_cvt_x<<<NASSIGN, 256, 0, stream>>>(x, perm, xgb);
  gemm1_kernel<<<MAXRT * (HFF / BN), 256, 0, stream>>>(xgb, W1t, b1, hb, ctrl);
  gemm2_kernel<<<MAXRT * (DMODEL / BN), 256, 0, stream>>>(hb, W2t, b2, wslot, y, ctrl);
  combine_kernel<<<TOK, 256, 0, stream>>>(y, ts, out);
}

// Round 4
// 835.213 us; speedup vs baseline: 1.1758x; 1.1758x over previous
//
#include <hip/hip_runtime.h>
#include <hip/hip_bf16.h>
#include <math.h>

// MoE: B=4 S=2048 D=1024 E=8 K=2 H=4096
// R7: occupancy is the measured lever (MfmaUtil ~= Occupancy across R3-R6).
//     Revert to R3's proven 128x128x64 single-buffer 2-barrier GEMM loop and
//     diet registers to fit 4 blocks/CU (16 waves):
//       - 1 staging pointer pair + compile-time i*32*LD offsets (was 4 pairs)
//       - aO/bO scalars; tm/tn become ds_read offset immediates (r&7==lm&7)
//       - __launch_bounds__(256,4): target <=64 VGPR + 64 acc = 128
//     gemm2: plain f32 stores to y + combine (atomic ceiling ~105 G/s would
//     bind at the predicted rate). Peripherals kept from R6 (fused transpose,
//     router-folded scan, no out-memset).

#define TOK     8192
#define DMODEL  1024
#define NEXP    8
#define HFF     4096
#define NASSIGN 16384
#define SLOTPAD 16512   // NASSIGN + 128 pad rows (partial-tile overreads)
#define BM      128
#define BN      128
#define BK      64
#define MAXRT   135     // sum_e ceil(n_e/128) <= 16384/128 + 7

typedef __attribute__((ext_vector_type(8))) short s16x8;
typedef __attribute__((ext_vector_type(4))) float f32x4;

__device__ __forceinline__ void gll16(const void* g, void* l) {
  __builtin_amdgcn_global_load_lds((const __attribute__((address_space(1))) void*)g,
                                   (__attribute__((address_space(3))) void*)l, 16, 0, 0);
}

// ---------- fused transpose + f32->bf16: W1 [D][H] -> W1t [H][D], W2 [H][D] -> W2t [D][H] ----------
__global__ void transpose_cvt(const float* __restrict__ W1, const float* __restrict__ W2,
                              __hip_bfloat16* __restrict__ W1t, __hip_bfloat16* __restrict__ W2t) {
  __shared__ float t[64][65];
  const int z = blockIdx.y;
  const float* src; __hip_bfloat16* dst; int R, C, bx, by;
  if (z < 8) {
    R = DMODEL; C = HFF;
    src = W1 + (size_t)z * R * C; dst = W1t + (size_t)z * R * C;
    bx = blockIdx.x & 63; by = blockIdx.x >> 6;     // 64 x 16 tiles
  } else {
    R = HFF; C = DMODEL;
    src = W2 + (size_t)(z - 8) * R * C; dst = W2t + (size_t)(z - 8) * R * C;
    bx = blockIdx.x & 15; by = blockIdx.x >> 4;     // 16 x 64 tiles
  }
  const int r0 = by * 64, c0 = bx * 64;
  const int tc = threadIdx.x & 63, tr = threadIdx.x >> 6;  // tr in 0..3
#pragma unroll
  for (int i = 0; i < 16; ++i) {
    int r = i * 4 + tr;
    t[r][tc] = src[(size_t)(r0 + r) * C + c0 + tc];
  }
  __syncthreads();
  const int jl = (threadIdx.x & 15) * 4;   // row offset within tile
  const int cw = threadIdx.x >> 4;         // 0..15: col within pass
#pragma unroll
  for (int p = 0; p < 4; ++p) {
    const int cc = p * 16 + cw;
    union { ushort4 u; __hip_bfloat16 h[4]; } o;
#pragma unroll
    for (int u = 0; u < 4; ++u) o.h[u] = __float2bfloat16(t[jl + u][cc]);
    *(ushort4*)(dst + (size_t)(c0 + cc) * R + r0 + jl) = o.u;
  }
}

// ---------- router: fp32 logits -> softmax -> top-2; last-done block performs the scan ----------
__global__ void router_kernel(const float* __restrict__ x, const float* __restrict__ Wg,
                              const float* __restrict__ bg, int* __restrict__ idx,
                              float* __restrict__ wtok, int* ctrl) {
  __shared__ int scnt[NEXP];
  if (threadIdx.x < NEXP) scnt[threadIdx.x] = 0;
  __syncthreads();
  const int wave = threadIdx.x >> 6, lane = threadIdx.x & 63;
  const int t = blockIdx.x * 4 + wave;
  float acc[NEXP];
#pragma unroll
  for (int e = 0; e < NEXP; ++e) acc[e] = 0.f;
  const float* xr = x + (size_t)t * DMODEL + lane * 16;
#pragma unroll
  for (int j = 0; j < 4; ++j) {
    float4 xv = *(const float4*)(xr + j * 4);
    const float* wr = Wg + (size_t)(lane * 16 + j * 4) * NEXP;
#pragma unroll
    for (int u = 0; u < 4; ++u) {
      float xs = (&xv.x)[u];
      float4 w0 = *(const float4*)(wr + u * NEXP);
      float4 w1 = *(const float4*)(wr + u * NEXP + 4);
      acc[0] += xs * w0.x; acc[1] += xs * w0.y; acc[2] += xs * w0.z; acc[3] += xs * w0.w;
      acc[4] += xs * w1.x; acc[5] += xs * w1.y; acc[6] += xs * w1.z; acc[7] += xs * w1.w;
    }
  }
#pragma unroll
  for (int off = 32; off >= 1; off >>= 1) {
#pragma unroll
    for (int e = 0; e < NEXP; ++e) acc[e] += __shfl_xor(acc[e], off, 64);
  }
  if (lane == 0) {
    float l[NEXP], m = -1e30f;
#pragma unroll
    for (int e = 0; e < NEXP; ++e) { l[e] = acc[e] + bg[e]; m = fmaxf(m, l[e]); }
    float p[NEXP], s = 0.f;
#pragma unroll
    for (int e = 0; e < NEXP; ++e) { p[e] = expf(l[e] - m); s += p[e]; }
    float inv = 1.f / s;
#pragma unroll
    for (int e = 0; e < NEXP; ++e) p[e] *= inv;
    int i0 = 0; float v0 = p[0];
#pragma unroll
    for (int e = 1; e < NEXP; ++e) if (p[e] > v0) { v0 = p[e]; i0 = e; }
    int i1 = -1; float v1 = -1e30f;
#pragma unroll
    for (int e = 0; e < NEXP; ++e) if (e != i0 && p[e] > v1) { v1 = p[e]; i1 = e; }
    idx[2 * t] = i0; idx[2 * t + 1] = i1;
    wtok[2 * t] = v0; wtok[2 * t + 1] = v1;
    atomicAdd(&scnt[i0], 1); atomicAdd(&scnt[i1], 1);
  }
  __syncthreads();
  if (threadIdx.x < NEXP) atomicAdd(&ctrl[threadIdx.x], scnt[threadIdx.x]);
  // ---- folded scan: last block to finish builds expOff/tileRowOff/cursor ----
  if (threadIdx.x == 0) {
    __threadfence();
    const int done = atomicAdd(&ctrl[63], 1);
    if (done == (int)gridDim.x - 1) {
      int c[NEXP];
#pragma unroll
      for (int e = 0; e < NEXP; ++e) c[e] = atomicAdd(&ctrl[e], 0);  // coherent read
      int eo = 0, tr = 0;
      ctrl[16] = 0; ctrl[26] = 0;
#pragma unroll
      for (int e = 0; e < NEXP; ++e) {
        ctrl[8 + e] = eo;            // cursor
        eo += c[e]; tr += (c[e] + BM - 1) / BM;
        ctrl[17 + e] = eo;           // expOff[e+1]
        ctrl[27 + e] = tr;           // tileRowOff[e+1]
      }
    }
  }
}

__global__ void scatter_kernel(const int* __restrict__ idx, const float* __restrict__ wtok,
                               int* ctrl, int* __restrict__ perm, int* __restrict__ ts,
                               float* __restrict__ wslot) {
  __shared__ int lcnt[NEXP];
  __shared__ int lbase[NEXP];
  const int t = blockIdx.x * 256 + threadIdx.x;
  if (threadIdx.x < NEXP) lcnt[threadIdx.x] = 0;
  __syncthreads();
  const int e0 = idx[2 * t], e1 = idx[2 * t + 1];
  const int l0 = atomicAdd(&lcnt[e0], 1);
  const int l1 = atomicAdd(&lcnt[e1], 1);
  __syncthreads();
  if (threadIdx.x < NEXP)
    lbase[threadIdx.x] = atomicAdd(&ctrl[8 + threadIdx.x], lcnt[threadIdx.x]);
  __syncthreads();
  const int s0 = lbase[e0] + l0, s1 = lbase[e1] + l1;
  perm[s0] = t; perm[s1] = t;
  ts[2 * t] = s0; ts[2 * t + 1] = s1;
  wslot[s0] = wtok[2 * t]; wslot[s1] = wtok[2 * t + 1];
}

__global__ void gather_cvt_x(const float* __restrict__ x, const int* __restrict__ perm,
                             __hip_bfloat16* __restrict__ xg) {
  const int slot = blockIdx.x;
  const int t = perm[slot];
  const float4 v = *(const float4*)(x + (size_t)t * DMODEL + threadIdx.x * 4);
  union { ushort4 u; __hip_bfloat16 h[4]; } o;
  o.h[0] = __float2bfloat16(v.x); o.h[1] = __float2bfloat16(v.y);
  o.h[2] = __float2bfloat16(v.z); o.h[3] = __float2bfloat16(v.w);
  *(ushort4*)(xg + (size_t)slot * DMODEL + threadIdx.x * 4) = o.u;
}

// ---- LDS layout (single buffer, 128 rows x BK=64): row r, 8 chunks of 8 bf16 (16B);
// chunk kc stored at slot kc ^ (r&7). Stage chunk s = tid+256*i: r=s>>3, sl=s&7,
// kc=sl^(r&7) -> lane-contiguous LDS dests (gll16-legal), pre-swizzled global src.
// r&7 is invariant under +16-row steps -> fragment offset = base + tm*1024 elems
// (folds into the ds_read offset immediate); k-half h flips bit 5 (^32).
// K-loop (R3-proven): stage 8 gll16; __syncthreads; 16 ds_read + 32 MFMA;
// __syncthreads.  4 blocks/CU target (32 KiB LDS, <=128 regs/wave).

// ---------- grouped GEMM1: h = gelu(xg @ W1t^T + b1) ----------
__global__ __launch_bounds__(256, 4) void gemm1_kernel(
    const __hip_bfloat16* __restrict__ xg, const __hip_bfloat16* __restrict__ w1t,
    const float* __restrict__ b1, __hip_bfloat16* __restrict__ hbuf,
    const int* __restrict__ ctrl) {
  const int* expOff = ctrl + 16;
  const int* tro = ctrl + 26;
  const int w = blockIdx.x;
  const int rt = w >> 5, nt = w & 31;   // rt-major
  if (rt >= tro[NEXP]) return;
  int e = 0;
#pragma unroll
  for (int q = 1; q < NEXP; ++q) if (tro[q] <= rt) e = q;
  const int rowBase = expOff[e] + (rt - tro[e]) * BM;
  const int rowEnd = expOff[e + 1];

  __shared__ __hip_bfloat16 lA[BM * BK];
  __shared__ __hip_bfloat16 lB[BN * BK];

  const int tid = threadIdx.x;
  const int lane = tid & 63, wave = tid >> 6;
  const int quad = lane >> 4, lm = lane & 15;
  const int waveM = (wave >> 1) * 64, waveN = (wave & 1) * 64;

  f32x4 acc[4][4];
#pragma unroll
  for (int a = 0; a < 4; ++a)
#pragma unroll
    for (int b = 0; b < 4; ++b) acc[a][b] = (f32x4){0.f, 0.f, 0.f, 0.f};

  const __hip_bfloat16* gA0;
  const __hip_bfloat16* gB0;
  {
    const int r = tid >> 3, kc = (tid & 7) ^ (r & 7);
    gA0 = xg + (size_t)(rowBase + r) * DMODEL + kc * 8;
    gB0 = w1t + (size_t)e * HFF * DMODEL + (size_t)nt * BN * DMODEL
              + (size_t)r * DMODEL + kc * 8;
  }

  const int aO = (waveM + lm) * 64 + ((quad ^ (lm & 7)) << 3);
  const int bO = (waveN + lm) * 64 + ((quad ^ (lm & 7)) << 3);

  for (int kt = 0; kt < DMODEL / BK; ++kt) {
#pragma unroll
    for (int i = 0; i < 4; ++i) {
      gll16(gA0 + (size_t)(i * 32) * DMODEL, lA + tid * 8 + i * 2048);
      gll16(gB0 + (size_t)(i * 32) * DMODEL, lB + tid * 8 + i * 2048);
    }
    gA0 += BK; gB0 += BK;
    __syncthreads();
#pragma unroll
    for (int h = 0; h < 2; ++h) {
      const __hip_bfloat16* pa = lA + (aO ^ (h * 32));
      const __hip_bfloat16* pb = lB + (bO ^ (h * 32));
      s16x8 af[4], bfr[4];
#pragma unroll
      for (int tm = 0; tm < 4; ++tm) af[tm] = *(const s16x8*)(pa + tm * 1024);
#pragma unroll
      for (int tn = 0; tn < 4; ++tn) bfr[tn] = *(const s16x8*)(pb + tn * 1024);
      __builtin_amdgcn_s_setprio(1);
#pragma unroll
      for (int tm = 0; tm < 4; ++tm)
#pragma unroll
        for (int tn = 0; tn < 4; ++tn)
          acc[tm][tn] = __builtin_amdgcn_mfma_f32_16x16x32_bf16(af[tm], bfr[tn],
                                                                acc[tm][tn], 0, 0, 0);
      __builtin_amdgcn_s_setprio(0);
    }
    __syncthreads();
  }

  const int colBase = nt * BN + waveN;
  float bv[4];
#pragma unroll
  for (int tn = 0; tn < 4; ++tn) bv[tn] = b1[e * HFF + colBase + tn * 16 + lm];
#pragma unroll
  for (int tm = 0; tm < 4; ++tm) {
    const int rb = rowBase + waveM + tm * 16 + quad * 4;
#pragma unroll
    for (int reg = 0; reg < 4; ++reg) {
      const int row = rb + reg;
      if (row < rowEnd) {
#pragma unroll
        for (int tn = 0; tn < 4; ++tn) {
          float v = acc[tm][tn][reg] + bv[tn];
          v = 0.5f * v * (1.f + erff(v * 0.70710678118654752f));  // exact gelu
          hbuf[(size_t)row * HFF + colBase + tn * 16 + lm] = __float2bfloat16(v);
        }
      }
    }
  }
}

// ---------- grouped GEMM2: y[slot] = (h @ W2t^T + b2) * w_gate   (plain f32 stores) ----------
__global__ __launch_bounds__(256, 4) void gemm2_kernel(
    const __hip_bfloat16* __restrict__ hbuf, const __hip_bfloat16* __restrict__ w2t,
    const float* __restrict__ b2, const float* __restrict__ wslot,
    float* __restrict__ y, const int* __restrict__ ctrl) {
  const int* expOff = ctrl + 16;
  const int* tro = ctrl + 26;
  const int w = blockIdx.x;
  const int rt = w >> 3, nt = w & 7;
  if (rt >= tro[NEXP]) return;
  int e = 0;
#pragma unroll
  for (int q = 1; q < NEXP; ++q) if (tro[q] <= rt) e = q;
  const int rowBase = expOff[e] + (rt - tro[e]) * BM;
  const int rowEnd = expOff[e + 1];

  __shared__ __hip_bfloat16 lA[BM * BK];
  __shared__ __hip_bfloat16 lB[BN * BK];

  const int tid = threadIdx.x;
  const int lane = tid & 63, wave = tid >> 6;
  const int quad = lane >> 4, lm = lane & 15;
  const int waveM = (wave >> 1) * 64, waveN = (wave & 1) * 64;

  f32x4 acc[4][4];
#pragma unroll
  for (int a = 0; a < 4; ++a)
#pragma unroll
    for (int b = 0; b < 4; ++b) acc[a][b] = (f32x4){0.f, 0.f, 0.f, 0.f};

  const __hip_bfloat16* gA0;
  const __hip_bfloat16* gB0;
  {
    const int r = tid >> 3, kc = (tid & 7) ^ (r & 7);
    gA0 = hbuf + (size_t)(rowBase + r) * HFF + kc * 8;
    gB0 = w2t + (size_t)e * DMODEL * HFF + (size_t)nt * BN * HFF
              + (size_t)r * HFF + kc * 8;
  }

  const int aO = (waveM + lm) * 64 + ((quad ^ (lm & 7)) << 3);
  const int bO = (waveN + lm) * 64 + ((quad ^ (lm & 7)) << 3);

  for (int kt = 0; kt < HFF / BK; ++kt) {
#pragma unroll
    for (int i = 0; i < 4; ++i) {
      gll16(gA0 + (size_t)(i * 32) * HFF, lA + tid * 8 + i * 2048);
      gll16(gB0 + (size_t)(i * 32) * HFF, lB + tid * 8 + i * 2048);
    }
    gA0 += BK; gB0 += BK;
    __syncthreads();
#pragma unroll
    for (int h = 0; h < 2; ++h) {
      const __hip_bfloat16* pa = lA + (aO ^ (h * 32));
      const __hip_bfloat16* pb = lB + (bO ^ (h * 32));
      s16x8 af[4], bfr[4];
#pragma unroll
      for (int tm = 0; tm < 4; ++tm) af[tm] = *(const s16x8*)(pa + tm * 1024);
#pragma unroll
      for (int tn = 0; tn < 4; ++tn) bfr[tn] = *(const s16x8*)(pb + tn * 1024);
      __builtin_amdgcn_s_setprio(1);
#pragma unroll
      for (int tm = 0; tm < 4; ++tm)
#pragma unroll
        for (int tn = 0; tn < 4; ++tn)
          acc[tm][tn] = __builtin_amdgcn_mfma_f32_16x16x32_bf16(af[tm], bfr[tn],
                                                                acc[tm][tn], 0, 0, 0);
      __builtin_amdgcn_s_setprio(0);
    }
    __syncthreads();
  }

  const int colBase = nt * BN + waveN;
  float bv[4];
#pragma unroll
  for (int tn = 0; tn < 4; ++tn) bv[tn] = b2[e * DMODEL + colBase + tn * 16 + lm];
#pragma unroll
  for (int tm = 0; tm < 4; ++tm) {
    const int rb = rowBase + waveM + tm * 16 + quad * 4;
#pragma unroll
    for (int reg = 0; reg < 4; ++reg) {
      const int row = rb + reg;
      if (row < rowEnd) {
        const float wr = wslot[row];
        float* yr = y + (size_t)row * DMODEL + colBase;
#pragma unroll
        for (int tn = 0; tn < 4; ++tn)
          yr[tn * 16 + lm] = (acc[tm][tn][reg] + bv[tn]) * wr;
      }
    }
  }
}

// ---------- combine: out[t] = y[slot0(t)] + y[slot1(t)]  (w already applied) ----------
__global__ void combine_kernel(const float* __restrict__ y, const int* __restrict__ ts,
                               float* __restrict__ out) {
  const int t = blockIdx.x;
  const int s0 = ts[2 * t], s1 = ts[2 * t + 1];
  const int c = threadIdx.x * 4;
  const float4 a = *(const float4*)(y + (size_t)s0 * DMODEL + c);
  const float4 b = *(const float4*)(y + (size_t)s1 * DMODEL + c);
  float4 r; r.x = a.x + b.x; r.y = a.y + b.y; r.z = a.z + b.z; r.w = a.w + b.w;
  *(float4*)(out + (size_t)t * DMODEL + c) = r;
}

extern "C" void kernel_launch(void* const* d_in, const int* in_sizes, int n_in,
                              void* d_out, int out_size, void* d_ws, size_t ws_size,
                              hipStream_t stream) {
  const float* x  = (const float*)d_in[0];
  const float* Wg = (const float*)d_in[1];
  const float* bg = (const float*)d_in[2];
  const float* W1 = (const float*)d_in[3];
  const float* b1 = (const float*)d_in[4];
  const float* W2 = (const float*)d_in[5];
  const float* b2 = (const float*)d_in[6];
  float* out = (float*)d_out;

  char* ws = (char*)d_ws;
  size_t off = 0;
  auto take = [&](size_t bytes) -> char* {
    char* p = ws + off;
    off = (off + bytes + 255) & ~(size_t)255;
    return p;
  };
  int*   ctrl  = (int*)take(64 * sizeof(int));
  int*   idx   = (int*)take((size_t)TOK * 2 * 4);
  float* wtok  = (float*)take((size_t)TOK * 2 * 4);
  int*   perm  = (int*)take((size_t)SLOTPAD * 4);
  int*   ts    = (int*)take((size_t)TOK * 2 * 4);
  float* wslot = (float*)take((size_t)SLOTPAD * 4);
  __hip_bfloat16* W1t = (__hip_bfloat16*)take((size_t)NEXP * HFF * DMODEL * 2);
  __hip_bfloat16* W2t = (__hip_bfloat16*)take((size_t)NEXP * DMODEL * HFF * 2);
  __hip_bfloat16* xgb = (__hip_bfloat16*)take((size_t)SLOTPAD * DMODEL * 2);
  __hip_bfloat16* hb  = (__hip_bfloat16*)take((size_t)SLOTPAD * HFF * 2);
  float* y = (float*)W1t;   // W1t dead after gemm1; used rows (<16384) fit exactly
  (void)ws_size; (void)in_sizes; (void)n_in; (void)out_size;

  hipMemsetAsync(ctrl, 0, 64 * sizeof(int), stream);
  transpose_cvt<<<dim3(1024, 16), 256, 0, stream>>>(W1, W2, W1t, W2t);
  router_kernel<<<TOK / 4, 256, 0, stream>>>(x, Wg, bg, idx, wtok, ctrl);
  scatter_kernel<<<TOK / 256, 256, 0, stream>>>(idx, wtok, ctrl, perm, ts, wslot);
  gather_cvt_x<<<NASSIGN, 256, 0, stream>>>(x, perm, xgb);
  gemm1_kernel<<<MAXRT * (HFF / BN), 256, 0, stream>>>(xgb, W1t, b1, hb, ctrl);
  gemm2_kernel<<<MAXRT * (DMODEL / BN), 256, 0, stream>>>(hb, W2t, b2, wslot, y, ctrl);
  combine_kernel<<<TOK, 256, 0, stream>>>(y, ts, out);
}